// Round 2
// baseline (333.714 us; speedup 1.0000x reference)
//
#include <hip/hip_runtime.h>

typedef unsigned short u16;
typedef unsigned int u32;
typedef __bf16 bf16x8 __attribute__((ext_vector_type(8)));
typedef float f32x4 __attribute__((ext_vector_type(4)));

__device__ __forceinline__ u16 f2bf(float f) {
  u32 u = __float_as_uint(f);
  return (u16)((u + 0x7fffu + ((u >> 16) & 1u)) >> 16);  // RNE
}
__device__ __forceinline__ float bf2f(u16 h) {
  return __uint_as_float(((u32)h) << 16);
}

// ---------------- x: fp32 -> bf16 ----------------
__global__ __launch_bounds__(256) void k_convert_x(const float4* __restrict__ x4,
                                                   uint2* __restrict__ o4, int n4) {
  int i = blockIdx.x * 256 + threadIdx.x;
  int stride = gridDim.x * 256;
  for (; i < n4; i += stride) {
    float4 v = x4[i];
    uint2 o;
    o.x = (u32)f2bf(v.x) | ((u32)f2bf(v.y) << 16);
    o.y = (u32)f2bf(v.z) | ((u32)f2bf(v.w) << 16);
    o4[i] = o;
  }
}

// ---------------- weight prep: transpose to [N][K] bf16, fold q scale ----------------
__global__ __launch_bounds__(256) void k_prep_w(
    const float* __restrict__ Wq, const float* __restrict__ bq,
    const float* __restrict__ Wkv, const float* __restrict__ bkv,
    const float* __restrict__ Wproj,
    u16* __restrict__ W1t, float* __restrict__ b1, u16* __restrict__ Wpt) {
  int n = blockIdx.x, k = threadIdx.x;
  if (n < 768) {
    float v = (n < 256) ? Wq[k * 256 + n] * 0.125f : Wkv[k * 512 + (n - 256)];
    W1t[n * 256 + k] = f2bf(v);
    if (k == 0) b1[n] = (n < 256) ? bq[n] * 0.125f : bkv[n - 256];
  } else {
    int nn = n - 768;
    Wpt[nn * 256 + k] = f2bf(Wproj[k * 256 + nn]);
  }
}

// ---------------- GEMM: C[M x N] = A[M x 256] * Bt[N x 256]^T + bias ----------------
// 128x128 tile, BK=32, 4 waves (2x2), 16x16x32 bf16 MFMA, 2-barrier loop, reg staging.
__global__ __launch_bounds__(256) void k_gemm(const u16* __restrict__ A,
                                              const u16* __restrict__ Bt,
                                              const float* __restrict__ bias,
                                              void* __restrict__ Cout,
                                              int N, int out_bf16) {
  __shared__ u16 As[128 * 32];
  __shared__ u16 Bs[128 * 32];
  int nt = N >> 7;
  int mt = blockIdx.x / nt;
  int ntile = blockIdx.x - mt * nt;
  int tid = threadIdx.x;
  int lane = tid & 63, wid = tid >> 6;
  int wm = wid >> 1, wn = wid & 1;
  size_t mbase = (size_t)mt << 7;
  int nbase = ntile << 7;
  int lrow = tid >> 2;           // 0..63
  int lch = (tid & 3) << 3;      // k-chunk * 8

  const u16* ag = A + (mbase + (size_t)lrow) * 256 + lch;
  const u16* bg = Bt + ((size_t)(nbase + lrow)) * 256 + lch;

  f32x4 acc[4][4] = {};

  for (int kb = 0; kb < 8; ++kb) {
    uint4 a0 = *(const uint4*)(ag + kb * 32);
    uint4 a1 = *(const uint4*)(ag + 64 * 256 + kb * 32);
    uint4 b0 = *(const uint4*)(bg + kb * 32);
    uint4 b1v = *(const uint4*)(bg + 64 * 256 + kb * 32);
    __syncthreads();
    *(uint4*)(As + tid * 8) = a0;
    *(uint4*)(As + 2048 + tid * 8) = a1;
    *(uint4*)(Bs + tid * 8) = b0;
    *(uint4*)(Bs + 2048 + tid * 8) = b1v;
    __syncthreads();
    int r = lane & 15, kq = (lane >> 4) << 3;
    bf16x8 af[4], bfv[4];
#pragma unroll
    for (int m = 0; m < 4; ++m)
      af[m] = *(const bf16x8*)(As + (wm * 64 + m * 16 + r) * 32 + kq);
#pragma unroll
    for (int n = 0; n < 4; ++n)
      bfv[n] = *(const bf16x8*)(Bs + (wn * 64 + n * 16 + r) * 32 + kq);
#pragma unroll
    for (int m = 0; m < 4; ++m)
#pragma unroll
      for (int n = 0; n < 4; ++n)
        acc[m][n] = __builtin_amdgcn_mfma_f32_16x16x32_bf16(af[m], bfv[n], acc[m][n], 0, 0, 0);
  }

  // epilogue: C/D layout col=lane&15, row=(lane>>4)*4+rr
  int cg4 = (lane >> 4) << 2;
  int cl = lane & 15;
#pragma unroll
  for (int m = 0; m < 4; ++m)
#pragma unroll
    for (int n = 0; n < 4; ++n) {
      size_t row0 = mbase + wm * 64 + m * 16 + cg4;
      int col = nbase + wn * 64 + n * 16 + cl;
      float bv = bias[col];
#pragma unroll
      for (int rr = 0; rr < 4; ++rr) {
        float v = acc[m][n][rr] + bv;
        if (out_bf16) ((u16*)Cout)[(row0 + rr) * (size_t)N + col] = f2bf(v);
        else ((float*)Cout)[(row0 + rr) * (size_t)N + col] = v;
      }
    }
}

// ---------------- attention + LePE ----------------
// One block per (d, b, line t). Line = column (d=0,1,3; roll via index map) or
// row (d=2). O = Q * (K^T V) per 16-dim head, + 3x3 depthwise LePE on windowed V.
// Source pixel for position p on line t:
//   d=0: (p, (t-(p+1))&127)   d=1: (p, (t+(p+1))&127)   d=3: (p, t)   d=2: (t, p)
//
// WRITE-BACK (the reference's _rev_* is applied with heads still folded into
// batch, which permutes the scatter):
//   batch2 = (b*16 + wb)*4 + n_h  ->  rev splits as (b', wb') = (B2//16, B2%16)
//   => out head-slot nf = wb>>2 = (t>>2)&3   (same for all lanes of a block)
//   => out line  tp = (t&112) | ((t&3)<<2) | n_h   (head goes into the column!)
//   d=0: (p,(tp-(p+1))&127)  d=1: (p,(tp+(p+1))&127)  d=3: (p,tp)  d=2: (tp,p)
//   out channel = d*64 + nf*16 + cl
__global__ __launch_bounds__(256) void k_attn(const u16* __restrict__ QKV,
                                              const float* __restrict__ lepe_w,
                                              const float* __restrict__ lepe_b,
                                              u16* __restrict__ Obuf) {
  __shared__ u16 Qs[128][64];
  __shared__ u16 Ks[128][64];
  __shared__ u16 Vs[128][64];
  __shared__ float Msm[4][16][16];
  __shared__ float lwS[9][16];
  __shared__ float lbS[16];

  int bid = blockIdx.x;
  int t = bid & 127;
  int b = (bid >> 7) & 3;
  int d = bid >> 9;
  int tid = threadIdx.x;

  if (tid < 144) lwS[tid >> 4][tid & 15] = lepe_w[(tid & 15) * 9 + (tid >> 4)];
  if (tid < 16) lbS[tid] = lepe_b[tid];

  // ---- stage line: 3 x 128 rows x 64ch bf16 ----
  int chunk = tid & 7;    // 8B-chunk of the 64-ch row
  int rb = tid >> 3;      // 0..31
#pragma unroll
  for (int i = 0; i < 4; ++i) {
    int p = i * 32 + rb;
    int h, w;
    if (d == 2)      { h = t; w = p; }
    else if (d == 0) { h = p; w = (t - (p + 1)) & 127; }
    else if (d == 1) { h = p; w = (t + (p + 1)) & 127; }
    else             { h = p; w = t; }
    size_t pix = ((size_t)(b * 128 + h) << 7) + w;
    const u16* src = QKV + pix * 768 + d * 64 + chunk * 8;
    *(uint4*)&Qs[p][chunk * 8] = *(const uint4*)(src);
    *(uint4*)&Ks[p][chunk * 8] = *(const uint4*)(src + 256);
    *(uint4*)&Vs[p][chunk * 8] = *(const uint4*)(src + 512);
  }
  __syncthreads();

  // ---- phase 1: M[head] = K^T V (16x16, fp32 accum), wave per head ----
  {
    int wid = tid >> 6, lane = tid & 63;
    int c1 = lane >> 2;            // 0..15
    int c2 = (lane & 3) << 2;      // 0,4,8,12
    int cb = wid << 4;
    float m0 = 0, m1 = 0, m2 = 0, m3 = 0;
#pragma unroll 4
    for (int p = 0; p < 128; ++p) {
      float kk = bf2f(Ks[p][cb + c1]);
      m0 += kk * bf2f(Vs[p][cb + c2 + 0]);
      m1 += kk * bf2f(Vs[p][cb + c2 + 1]);
      m2 += kk * bf2f(Vs[p][cb + c2 + 2]);
      m3 += kk * bf2f(Vs[p][cb + c2 + 3]);
    }
    Msm[wid][c1][c2 + 0] = m0;
    Msm[wid][c1][c2 + 1] = m1;
    Msm[wid][c1][c2 + 2] = m2;
    Msm[wid][c1][c2 + 3] = m3;
  }
  __syncthreads();

  // ---- phase 2: lanes = channels (row-contiguous LDS / coalesced global) ----
  int c = tid & 63;        // channel within this direction's 64
  int p0 = tid >> 6;       // wave id -> 32 consecutive positions
  int hh = c >> 4;         // head
  int cl = c & 15;         // channel within head (LePE filter index)
  float Mreg[16];
#pragma unroll
  for (int c1 = 0; c1 < 16; ++c1) Mreg[c1] = Msm[hh][c1][cl];
  float wreg[9];
#pragma unroll
  for (int k = 0; k < 9; ++k) wreg[k] = lwS[k][cl];
  float lbias = lbS[cl];
  int si = t >> 4, wb = t & 15;
  const u16* Vg = QKV + 512 + d * 64 + c;  // + pix*768 per gather

  // permuted write-back coordinates (see header comment)
  int nf = (t >> 2) & 3;                        // output head-slot
  int tp = (t & 112) | ((t & 3) << 2) | hh;     // permuted output line
  int och = d * 64 + nf * 16 + cl;

  for (int ii = 0; ii < 32; ++ii) {
    int p = p0 * 32 + ii;
    // attention: o = q . M
    float acc = 0.f;
#pragma unroll
    for (int c1 = 0; c1 < 16; ++c1) acc += Mreg[c1] * bf2f(Qs[p][hh * 16 + c1]);
    // LePE center column (window-offset a=0): rows p-1..p+1 from LDS
#pragma unroll
    for (int bb = -1; bb <= 1; ++bb) {
      int pp = p + bb;
      if (pp >= 0 && pp < 128) acc += wreg[3 + (bb + 1)] * bf2f(Vs[pp][c]);
    }
    // LePE side columns (a=+-1 -> lines t+-16), coalesced 2B/lane gathers
#pragma unroll
    for (int a = -1; a <= 1; a += 2) {
      int s2 = si + a;
      if (s2 < 0 || s2 >= 8) continue;
      int line2 = (s2 << 4) + wb;
#pragma unroll
      for (int bb = -1; bb <= 1; ++bb) {
        int pp = p + bb;
        if (pp < 0 || pp >= 128) continue;
        int h2, w2;
        if (d == 2)      { h2 = line2; w2 = pp; }
        else if (d == 0) { h2 = pp; w2 = (line2 - (pp + 1)) & 127; }
        else if (d == 1) { h2 = pp; w2 = (line2 + (pp + 1)) & 127; }
        else             { h2 = pp; w2 = line2; }
        size_t pix = ((size_t)(b * 128 + h2) << 7) + w2;
        acc += wreg[(a + 1) * 3 + (bb + 1)] * bf2f(Vg[pix * 768]);
      }
    }
    acc += lbias;
    // write to permuted destination pixel
    int ho, wo;
    if (d == 2)      { ho = tp; wo = p; }
    else if (d == 0) { ho = p; wo = (tp - (p + 1)) & 127; }
    else if (d == 1) { ho = p; wo = (tp + (p + 1)) & 127; }
    else             { ho = p; wo = tp; }
    size_t opix = ((size_t)(b * 128 + ho) << 7) + wo;
    Obuf[opix * 256 + och] = f2bf(acc);
  }
}

// ---------------- launch ----------------
extern "C" void kernel_launch(void* const* d_in, const int* in_sizes, int n_in,
                              void* d_out, int out_size, void* d_ws, size_t ws_size,
                              hipStream_t stream) {
  (void)in_sizes; (void)n_in; (void)out_size; (void)ws_size;
  const float* x     = (const float*)d_in[0];
  const float* Wq    = (const float*)d_in[1];
  const float* bq    = (const float*)d_in[2];
  const float* Wkv   = (const float*)d_in[3];
  const float* bkv   = (const float*)d_in[4];
  const float* Wproj = (const float*)d_in[5];
  const float* bproj = (const float*)d_in[6];
  const float* lepe_w = (const float*)d_in[7];
  const float* lepe_b = (const float*)d_in[8];
  float* out = (float*)d_out;

  // workspace layout (bytes): total ~160.5 MiB
  char* ws = (char*)d_ws;
  u16* Xbf   = (u16*)(ws + 0);           //  65536x256 bf16 = 32 MB
  u16* QKV   = (u16*)(ws + 33554432);    //  65536x768 bf16 = 96 MB
  u16* Obuf  = (u16*)(ws + 134217728);   //  65536x256 bf16 = 32 MB
  u16* W1t   = (u16*)(ws + 167772160);   //  768x256 bf16
  u16* Wpt   = (u16*)(ws + 168165376);   //  256x256 bf16
  float* b1  = (float*)(ws + 168296448); //  768 f32

  k_convert_x<<<2048, 256, 0, stream>>>((const float4*)x, (uint2*)Xbf, 16777216 / 4);
  k_prep_w<<<1024, 256, 0, stream>>>(Wq, bq, Wkv, bkv, Wproj, W1t, b1, Wpt);
  k_gemm<<<512 * 6, 256, 0, stream>>>(Xbf, W1t, b1, QKV, 768, 1);
  k_attn<<<2048, 256, 0, stream>>>(QKV, lepe_w, lepe_b, Obuf);
  k_gemm<<<512 * 2, 256, 0, stream>>>(Obuf, Wpt, bproj, out, 256, 0);
}

// Round 4
// 168.568 us; speedup vs baseline: 1.9797x; 1.9797x over previous
//
#include <hip/hip_runtime.h>

typedef unsigned short u16;
typedef unsigned int u32;
typedef unsigned long long u64;
typedef __bf16 bf16x8 __attribute__((ext_vector_type(8)));
typedef float f32x4 __attribute__((ext_vector_type(4)));

__device__ __forceinline__ u16 f2bf(float f) {
  u32 u = __float_as_uint(f);
  return (u16)((u + 0x7fffu + ((u >> 16) & 1u)) >> 16);  // RNE
}
__device__ __forceinline__ float bf2f(u16 h) {
  return __uint_as_float(((u32)h) << 16);
}

// ---------------- x: fp32 -> bf16 ----------------
__global__ __launch_bounds__(256) void k_convert_x(const float4* __restrict__ x4,
                                                   uint2* __restrict__ o4, int n4) {
  int i = blockIdx.x * 256 + threadIdx.x;
  int stride = gridDim.x * 256;
  for (; i < n4; i += stride) {
    float4 v = x4[i];
    uint2 o;
    o.x = (u32)f2bf(v.x) | ((u32)f2bf(v.y) << 16);
    o.y = (u32)f2bf(v.z) | ((u32)f2bf(v.w) << 16);
    o4[i] = o;
  }
}

// ---------------- weight prep ----------------
__global__ __launch_bounds__(256) void k_prep_w(
    const float* __restrict__ Wq, const float* __restrict__ bq,
    const float* __restrict__ Wkv, const float* __restrict__ bkv,
    const float* __restrict__ Wproj,
    u16* __restrict__ W1t, float* __restrict__ b1, u16* __restrict__ Wpt) {
  int n = blockIdx.x, k = threadIdx.x;
  if (n < 768) {
    float v = (n < 256) ? Wq[k * 256 + n] * 0.125f : Wkv[k * 512 + (n - 256)];
    W1t[n * 256 + k] = f2bf(v);
    if (k == 0) b1[n] = (n < 256) ? bq[n] * 0.125f : bkv[n - 256];
  } else {
    int nn = n - 768;
    Wpt[nn * 256 + k] = f2bf(Wproj[k * 256 + nn]);
  }
}

// ---------------- GEMM (round-1 VERIFIED version, unchanged) ----------------
__global__ __launch_bounds__(256) void k_gemm(const u16* __restrict__ A,
                                              const u16* __restrict__ Bt,
                                              const float* __restrict__ bias,
                                              void* __restrict__ Cout,
                                              int N, int out_bf16) {
  __shared__ u16 As[128 * 32];
  __shared__ u16 Bs[128 * 32];
  int nt = N >> 7;
  int mt = blockIdx.x / nt;
  int ntile = blockIdx.x - mt * nt;
  int tid = threadIdx.x;
  int lane = tid & 63, wid = tid >> 6;
  int wm = wid >> 1, wn = wid & 1;
  size_t mbase = (size_t)mt << 7;
  int nbase = ntile << 7;
  int lrow = tid >> 2;
  int lch = (tid & 3) << 3;

  const u16* ag = A + (mbase + (size_t)lrow) * 256 + lch;
  const u16* bg = Bt + ((size_t)(nbase + lrow)) * 256 + lch;

  f32x4 acc[4][4] = {};

  for (int kb = 0; kb < 8; ++kb) {
    uint4 a0 = *(const uint4*)(ag + kb * 32);
    uint4 a1 = *(const uint4*)(ag + 64 * 256 + kb * 32);
    uint4 b0 = *(const uint4*)(bg + kb * 32);
    uint4 b1v = *(const uint4*)(bg + 64 * 256 + kb * 32);
    __syncthreads();
    *(uint4*)(As + tid * 8) = a0;
    *(uint4*)(As + 2048 + tid * 8) = a1;
    *(uint4*)(Bs + tid * 8) = b0;
    *(uint4*)(Bs + 2048 + tid * 8) = b1v;
    __syncthreads();
    int r = lane & 15, kq = (lane >> 4) << 3;
    bf16x8 af[4], bfv[4];
#pragma unroll
    for (int m = 0; m < 4; ++m)
      af[m] = *(const bf16x8*)(As + (wm * 64 + m * 16 + r) * 32 + kq);
#pragma unroll
    for (int n = 0; n < 4; ++n)
      bfv[n] = *(const bf16x8*)(Bs + (wn * 64 + n * 16 + r) * 32 + kq);
#pragma unroll
    for (int m = 0; m < 4; ++m)
#pragma unroll
      for (int n = 0; n < 4; ++n)
        acc[m][n] = __builtin_amdgcn_mfma_f32_16x16x32_bf16(af[m], bfv[n], acc[m][n], 0, 0, 0);
  }

  int cg4 = (lane >> 4) << 2;
  int cl = lane & 15;
#pragma unroll
  for (int m = 0; m < 4; ++m)
#pragma unroll
    for (int n = 0; n < 4; ++n) {
      size_t row0 = mbase + wm * 64 + m * 16 + cg4;
      int col = nbase + wn * 64 + n * 16 + cl;
      float bv = bias[col];
#pragma unroll
      for (int rr = 0; rr < 4; ++rr) {
        float v = acc[m][n][rr] + bv;
        if (out_bf16) ((u16*)Cout)[(row0 + rr) * (size_t)N + col] = f2bf(v);
        else ((float*)Cout)[(row0 + rr) * (size_t)N + col] = v;
      }
    }
}

// ---------------- attention + LePE (MFMA, verified primitives only) ----------------
// Block = (d, b, line t), 512 threads = 8 waves.
// LDS: K, V(t), V(t-16), V(t+16) column-major [c][p] u16, swizzled:
//   byte(c, p) = c*256 + ((2p) ^ ((c&7)<<4))      (16B-granule XOR)
// Phase 1: M_head = K^T V via 16x16x32 MFMA, A/B frags = contiguous-p b128 reads
//   (same fragment mapping as the verified k_gemm). Wave w: head w&3, p-half w>>2.
//   Halves summed fp32 -> Mt bf16 [head][c2][c1 padded to 32, upper 16 zero].
// Phase 2: O = Q*M via MFMA (Q A-frags prefetched from global into regs);
//   LePE 3x3 conv taps all LDS-local. Write-back permutation = round-1 verified.
__global__ __launch_bounds__(512) void k_attn(const u16* __restrict__ QKV,
                                              const float* __restrict__ lepe_w,
                                              const float* __restrict__ lepe_b,
                                              u16* __restrict__ Obuf) {
  __shared__ u16 BUF[4][64 * 128];   // 0:K 1:Vo 2:Vm 3:Vp  (16 KB each)
  __shared__ float Mf[8][16][16];    // per-wave partial M (f32)
  __shared__ u16 Mt[4][16][32];      // M^T bf16, K-padded to 32
  __shared__ float lwS[9][16];
  __shared__ float lbS[16];

  int bid = blockIdx.x;
  int t = bid & 127, b = (bid >> 7) & 3, d = bid >> 9;
  int tid = threadIdx.x;
  int w = tid >> 6, l = tid & 63;
  int hh = w & 3, ph = w >> 2;

  // zero Mt (4096 B = 1024 u32)
  ((u32*)Mt)[tid] = 0;
  ((u32*)Mt)[tid + 512] = 0;
  if (tid < 144) lwS[tid >> 4][tid & 15] = lepe_w[(tid & 15) * 9 + (tid >> 4)];
  if (tid < 16) lbS[tid] = lepe_b[tid];

  auto pixof = [&](int line, int p) -> u32 {
    int h, ww;
    if (d == 2)      { h = line; ww = p; }
    else if (d == 0) { h = p; ww = (line - (p + 1)) & 127; }
    else if (d == 1) { h = p; ww = (line + (p + 1)) & 127; }
    else             { h = p; ww = line; }
    return ((u32)(b * 128 + h) << 7) + (u32)ww;
  };

  // ---- Q prefetch into regs: wave w -> head hh, ptiles ph*4+k ----
  // A-frag: row = l&15 (p within tile), k-chunk duplicated for l>>4>=2 (B zero there)
  uint4 qreg[4];
  u32 qch = (u32)d * 64 + (u32)hh * 16 + (u32)((l >> 4) & 1) * 8;
#pragma unroll
  for (int k = 0; k < 4; ++k) {
    int p = (ph * 4 + k) * 16 + (l & 15);
    qreg[k] = *(const uint4*)(QKV + (u64)pixof(t, p) * 768 + qch);
  }

  // ---- stage: wave w -> buffer w&3, p-half w>>2; lane = channel ----
  {
    int bf = w & 3;
    int p0s = (w >> 2) * 64;
    int line = t;
    u32 choff = (bf == 0) ? (256u + d * 64) : (512u + d * 64);
    bool ok = true;
    if (bf == 2) { line = t - 16; ok = (t >> 4) > 0; }
    if (bf == 3) { line = t + 16; ok = (t >> 4) < 7; }
    char* B = (char*)BUF[bf] + (u32)l * 256;
    u32 sw = ((u32)(l & 7)) << 4;
#pragma unroll
    for (int g8 = 0; g8 < 8; ++g8) {
      int pb = p0s + g8 * 8;
      uint4 val = make_uint4(0, 0, 0, 0);
      if (ok) {
        u16 e0 = QKV[(u64)pixof(line, pb + 0) * 768 + choff + l];
        u16 e1 = QKV[(u64)pixof(line, pb + 1) * 768 + choff + l];
        u16 e2 = QKV[(u64)pixof(line, pb + 2) * 768 + choff + l];
        u16 e3 = QKV[(u64)pixof(line, pb + 3) * 768 + choff + l];
        u16 e4 = QKV[(u64)pixof(line, pb + 4) * 768 + choff + l];
        u16 e5 = QKV[(u64)pixof(line, pb + 5) * 768 + choff + l];
        u16 e6 = QKV[(u64)pixof(line, pb + 6) * 768 + choff + l];
        u16 e7 = QKV[(u64)pixof(line, pb + 7) * 768 + choff + l];
        val.x = (u32)e0 | ((u32)e1 << 16);
        val.y = (u32)e2 | ((u32)e3 << 16);
        val.z = (u32)e4 | ((u32)e5 << 16);
        val.w = (u32)e6 | ((u32)e7 << 16);
      }
      *(uint4*)(B + (((u32)(2 * pb)) ^ sw)) = val;
    }
  }
  __syncthreads();

  // ---- phase 1: wave w computes partial M for head hh over p-half ph ----
  {
    u32 cA = (u32)hh * 16 + (u32)(l & 15);   // c1 for K-frag, c2 for V-frag
    u32 rowb = cA * 256;
    u32 sw = (cA & 7) << 4;
    f32x4 m = {0.f, 0.f, 0.f, 0.f};
#pragma unroll
    for (int kc = 0; kc < 2; ++kc) {
      u32 pc = (u32)ph * 64 + (u32)kc * 32 + (u32)(l >> 4) * 8;
      u32 off = rowb + (((u32)(2 * pc)) ^ sw);
      bf16x8 ka = *(const bf16x8*)((const char*)BUF[0] + off);
      bf16x8 vb = *(const bf16x8*)((const char*)BUF[1] + off);
      m = __builtin_amdgcn_mfma_f32_16x16x32_bf16(ka, vb, m, 0, 0, 0);
    }
    // D: col=l&15 = c2, row=(l>>4)*4+rr = c1 -> Mf[w][c2][c1] (f32x4 contiguous)
    *(f32x4*)&Mf[w][l & 15][(l >> 4) * 4] = m;
  }
  __syncthreads();

  // ---- combine halves -> Mt bf16 ----
  if (tid < 256) {
    int ch = tid >> 6;
    int c2 = (tid >> 2) & 15;
    int c1g = (tid & 3) * 4;
    f32x4 a = *(const f32x4*)&Mf[ch][c2][c1g];
    f32x4 bb = *(const f32x4*)&Mf[ch + 4][c2][c1g];
    u16* dst = &Mt[ch][c2][c1g];
    dst[0] = f2bf(a[0] + bb[0]);
    dst[1] = f2bf(a[1] + bb[1]);
    dst[2] = f2bf(a[2] + bb[2]);
    dst[3] = f2bf(a[3] + bb[3]);
  }
  __syncthreads();

  // ---- phase 2: O = Q*M + LePE conv + permuted store ----
  union UB { uint4 u; bf16x8 v; } mb;
  mb.u = *(const uint4*)((const char*)Mt + (u32)hh * 1024 + (u32)(l & 15) * 64 +
                         (u32)(l >> 4) * 16);

  float wreg[9];
#pragma unroll
  for (int k = 0; k < 9; ++k) wreg[k] = lwS[k][l & 15];
  float lbias = lbS[l & 15];
  int nf = (t >> 2) & 3;                     // output head-slot
  int tp = (t & 112) | ((t & 3) << 2) | hh;  // permuted output line
  u32 och = (u32)d * 64 + (u32)nf * 16 + (u32)(l & 15);
  u32 cc = (u32)hh * 16 + (u32)(l & 15);
  u32 ccb = cc * 256;
  u32 csw = (cc & 7) << 4;
  int g = l >> 4;

#pragma unroll
  for (int k = 0; k < 4; ++k) {
    int pt = ph * 4 + k;
    union UA { uint4 u; bf16x8 v; } qa;
    qa.u = qreg[k];
    f32x4 o = {0.f, 0.f, 0.f, 0.f};
    o = __builtin_amdgcn_mfma_f32_16x16x32_bf16(qa.v, mb.v, o, 0, 0, 0);

    int p0 = pt * 16 + g * 4;
    // conv taps: rows = {Vm(BUF2), Vo(BUF1), Vp(BUF3)} x p0-1..p0+4
    float tap[3][6];
    const u32 bufid[3] = {2u, 1u, 3u};
#pragma unroll
    for (int r = 0; r < 3; ++r) {
      const char* Bp = (const char*)BUF[bufid[r]] + ccb;
      union { uint2 u; u16 e[4]; } m4;
      m4.u = *(const uint2*)(Bp + (((u32)(2 * p0)) ^ csw));
      u32 alo = (p0 > 0) ? ((u32)(2 * (p0 - 1)) ^ csw) : csw;
      u32 ahi = (p0 < 124) ? ((u32)(2 * (p0 + 4)) ^ csw) : csw;
      u16 loe = *(const u16*)(Bp + alo);
      u16 hie = *(const u16*)(Bp + ahi);
      tap[r][0] = (p0 > 0) ? bf2f(loe) : 0.f;
      tap[r][1] = bf2f(m4.e[0]);
      tap[r][2] = bf2f(m4.e[1]);
      tap[r][3] = bf2f(m4.e[2]);
      tap[r][4] = bf2f(m4.e[3]);
      tap[r][5] = (p0 < 124) ? bf2f(hie) : 0.f;
    }
#pragma unroll
    for (int rr = 0; rr < 4; ++rr) {
      float acc = o[rr] + lbias;
#pragma unroll
      for (int r = 0; r < 3; ++r)
#pragma unroll
        for (int bb = 0; bb < 3; ++bb)
          acc += wreg[r * 3 + bb] * tap[r][rr + bb];
      int p = p0 + rr;
      int ho, wo;
      if (d == 2)      { ho = tp; wo = p; }
      else if (d == 0) { ho = p; wo = (tp - (p + 1)) & 127; }
      else if (d == 1) { ho = p; wo = (tp + (p + 1)) & 127; }
      else             { ho = p; wo = tp; }
      u32 opix = ((u32)(b * 128 + ho) << 7) + (u32)wo;
      Obuf[opix * 256 + och] = f2bf(acc);
    }
  }
}

// ---------------- launch ----------------
extern "C" void kernel_launch(void* const* d_in, const int* in_sizes, int n_in,
                              void* d_out, int out_size, void* d_ws, size_t ws_size,
                              hipStream_t stream) {
  (void)in_sizes; (void)n_in; (void)out_size; (void)ws_size;
  const float* x     = (const float*)d_in[0];
  const float* Wq    = (const float*)d_in[1];
  const float* bq    = (const float*)d_in[2];
  const float* Wkv   = (const float*)d_in[3];
  const float* bkv   = (const float*)d_in[4];
  const float* Wproj = (const float*)d_in[5];
  const float* bproj = (const float*)d_in[6];
  const float* lepe_w = (const float*)d_in[7];
  const float* lepe_b = (const float*)d_in[8];
  float* out = (float*)d_out;

  char* ws = (char*)d_ws;
  u16* Xbf   = (u16*)(ws + 0);           //  65536x256 bf16 = 32 MB
  u16* QKV   = (u16*)(ws + 33554432);    //  65536x768 bf16 = 96 MB
  u16* Obuf  = (u16*)(ws + 134217728);   //  65536x256 bf16 = 32 MB
  u16* W1t   = (u16*)(ws + 167772160);   //  768x256 bf16
  u16* Wpt   = (u16*)(ws + 168165376);   //  256x256 bf16
  float* b1  = (float*)(ws + 168296448); //  768 f32

  k_convert_x<<<2048, 256, 0, stream>>>((const float4*)x, (uint2*)Xbf, 16777216 / 4);
  k_prep_w<<<1024, 256, 0, stream>>>(Wq, bq, Wkv, bkv, Wproj, W1t, b1, Wpt);
  k_gemm<<<512 * 6, 256, 0, stream>>>(Xbf, W1t, b1, QKV, 768, 1);
  k_attn<<<2048, 512, 0, stream>>>(QKV, lepe_w, lepe_b, Obuf);
  k_gemm<<<512 * 2, 256, 0, stream>>>(Obuf, Wpt, bproj, out, 256, 0);
}

// Round 5
// 152.387 us; speedup vs baseline: 2.1899x; 1.1062x over previous
//
#include <hip/hip_runtime.h>

typedef unsigned short u16;
typedef unsigned int u32;
typedef unsigned long long u64;
typedef __bf16 bf16x8 __attribute__((ext_vector_type(8)));
typedef float f32x4 __attribute__((ext_vector_type(4)));

__device__ __forceinline__ u16 f2bf(float f) {
  u32 u = __float_as_uint(f);
  return (u16)((u + 0x7fffu + ((u >> 16) & 1u)) >> 16);  // RNE
}
__device__ __forceinline__ float bf2f(u16 h) {
  return __uint_as_float(((u32)h) << 16);
}

// async global->LDS, 16B per lane; HW writes wave-uniform LDS base + lane*16
__device__ __forceinline__ void glds16(const void* g, void* s) {
  __builtin_amdgcn_global_load_lds(
      (__attribute__((address_space(1))) void*)(u64)g,
      (__attribute__((address_space(3))) void*)(u32)(u64)s, 16, 0, 0);
}

// ---------------- x: fp32 -> bf16 ----------------
__global__ __launch_bounds__(256) void k_convert_x(const float4* __restrict__ x4,
                                                   uint2* __restrict__ o4, int n4) {
  int i = blockIdx.x * 256 + threadIdx.x;
  int stride = gridDim.x * 256;
  for (; i < n4; i += stride) {
    float4 v = x4[i];
    uint2 o;
    o.x = (u32)f2bf(v.x) | ((u32)f2bf(v.y) << 16);
    o.y = (u32)f2bf(v.z) | ((u32)f2bf(v.w) << 16);
    o4[i] = o;
  }
}

// ---------------- weight prep ----------------
__global__ __launch_bounds__(256) void k_prep_w(
    const float* __restrict__ Wq, const float* __restrict__ bq,
    const float* __restrict__ Wkv, const float* __restrict__ bkv,
    const float* __restrict__ Wproj,
    u16* __restrict__ W1t, float* __restrict__ b1, u16* __restrict__ Wpt) {
  int n = blockIdx.x, k = threadIdx.x;
  if (n < 768) {
    float v = (n < 256) ? Wq[k * 256 + n] * 0.125f : Wkv[k * 512 + (n - 256)];
    W1t[n * 256 + k] = f2bf(v);
    if (k == 0) b1[n] = (n < 256) ? bq[n] * 0.125f : bkv[n - 256];
  } else {
    int nn = n - 768;
    Wpt[nn * 256 + k] = f2bf(Wproj[k * 256 + nn]);
  }
}

// ---------------- GEMM: C[M x N] = A[M x 256] * Bt[N x 256]^T + bias ----------------
// 128x128 tile, BK=32, 4 waves (2x2), 16x16x32 bf16 MFMA.
// global_load_lds(16B) staging + XCD-chunked block swizzle (nwg % 8 == 0).
__global__ __launch_bounds__(256) void k_gemm(const u16* __restrict__ A,
                                              const u16* __restrict__ Bt,
                                              const float* __restrict__ bias,
                                              void* __restrict__ Cout,
                                              int N, int out_bf16) {
  __shared__ u16 As[128 * 32];
  __shared__ u16 Bs[128 * 32];
  int nt = N >> 7;
  int nwg = gridDim.x;
  int bid = blockIdx.x;
  // XCD-chunked swizzle: blocks with bid%8==x (dispatched to XCD x) get a
  // contiguous chunk of tile-space -> all N-tiles of an M-tile share one L2.
  int swz = (bid & 7) * (nwg >> 3) + (bid >> 3);
  int mt = swz / nt;
  int ntile = swz - mt * nt;
  int tid = threadIdx.x;
  int lane = tid & 63, wid = tid >> 6;
  int wm = wid >> 1, wn = wid & 1;
  size_t mbase = (size_t)mt << 7;
  int nbase = ntile << 7;
  int lrow = tid >> 2;           // 0..63
  int lch = (tid & 3) << 3;      // k-chunk * 8

  const u16* ag = A + (mbase + (size_t)lrow) * 256 + lch;
  const u16* bg = Bt + ((size_t)(nbase + lrow)) * 256 + lch;
  u32 wbase = ((u32)wid) << 9;   // wave-uniform LDS base, u16 units (w*1024 B)

  f32x4 acc[4][4] = {};

  for (int kb = 0; kb < 8; ++kb) {
    __syncthreads();
    glds16(ag + kb * 32, As + wbase);
    glds16(ag + 64 * 256 + kb * 32, As + 2048 + wbase);
    glds16(bg + kb * 32, Bs + wbase);
    glds16(bg + 64 * 256 + kb * 32, Bs + 2048 + wbase);
    __syncthreads();
    int r = lane & 15, kq = (lane >> 4) << 3;
    bf16x8 af[4], bfv[4];
#pragma unroll
    for (int m = 0; m < 4; ++m)
      af[m] = *(const bf16x8*)(As + (wm * 64 + m * 16 + r) * 32 + kq);
#pragma unroll
    for (int n = 0; n < 4; ++n)
      bfv[n] = *(const bf16x8*)(Bs + (wn * 64 + n * 16 + r) * 32 + kq);
#pragma unroll
    for (int m = 0; m < 4; ++m)
#pragma unroll
      for (int n = 0; n < 4; ++n)
        acc[m][n] = __builtin_amdgcn_mfma_f32_16x16x32_bf16(af[m], bfv[n], acc[m][n], 0, 0, 0);
  }

  int cg4 = (lane >> 4) << 2;
  int cl = lane & 15;
#pragma unroll
  for (int m = 0; m < 4; ++m)
#pragma unroll
    for (int n = 0; n < 4; ++n) {
      size_t row0 = mbase + wm * 64 + m * 16 + cg4;
      int col = nbase + wn * 64 + n * 16 + cl;
      float bv = bias[col];
#pragma unroll
      for (int rr = 0; rr < 4; ++rr) {
        float v = acc[m][n][rr] + bv;
        if (out_bf16) ((u16*)Cout)[(row0 + rr) * (size_t)N + col] = f2bf(v);
        else ((float*)Cout)[(row0 + rr) * (size_t)N + col] = v;
      }
    }
}

// ---------------- attention + LePE (round-4 VERIFIED version, unchanged) ----------------
__global__ __launch_bounds__(512) void k_attn(const u16* __restrict__ QKV,
                                              const float* __restrict__ lepe_w,
                                              const float* __restrict__ lepe_b,
                                              u16* __restrict__ Obuf) {
  __shared__ u16 BUF[4][64 * 128];   // 0:K 1:Vo 2:Vm 3:Vp  (16 KB each)
  __shared__ float Mf[8][16][16];    // per-wave partial M (f32)
  __shared__ u16 Mt[4][16][32];      // M^T bf16, K-padded to 32
  __shared__ float lwS[9][16];
  __shared__ float lbS[16];

  int bid = blockIdx.x;
  int t = bid & 127, b = (bid >> 7) & 3, d = bid >> 9;
  int tid = threadIdx.x;
  int w = tid >> 6, l = tid & 63;
  int hh = w & 3, ph = w >> 2;

  ((u32*)Mt)[tid] = 0;
  ((u32*)Mt)[tid + 512] = 0;
  if (tid < 144) lwS[tid >> 4][tid & 15] = lepe_w[(tid & 15) * 9 + (tid >> 4)];
  if (tid < 16) lbS[tid] = lepe_b[tid];

  auto pixof = [&](int line, int p) -> u32 {
    int h, ww;
    if (d == 2)      { h = line; ww = p; }
    else if (d == 0) { h = p; ww = (line - (p + 1)) & 127; }
    else if (d == 1) { h = p; ww = (line + (p + 1)) & 127; }
    else             { h = p; ww = line; }
    return ((u32)(b * 128 + h) << 7) + (u32)ww;
  };

  uint4 qreg[4];
  u32 qch = (u32)d * 64 + (u32)hh * 16 + (u32)((l >> 4) & 1) * 8;
#pragma unroll
  for (int k = 0; k < 4; ++k) {
    int p = (ph * 4 + k) * 16 + (l & 15);
    qreg[k] = *(const uint4*)(QKV + (u64)pixof(t, p) * 768 + qch);
  }

  {
    int bf = w & 3;
    int p0s = (w >> 2) * 64;
    int line = t;
    u32 choff = (bf == 0) ? (256u + d * 64) : (512u + d * 64);
    bool ok = true;
    if (bf == 2) { line = t - 16; ok = (t >> 4) > 0; }
    if (bf == 3) { line = t + 16; ok = (t >> 4) < 7; }
    char* B = (char*)BUF[bf] + (u32)l * 256;
    u32 sw = ((u32)(l & 7)) << 4;
#pragma unroll
    for (int g8 = 0; g8 < 8; ++g8) {
      int pb = p0s + g8 * 8;
      uint4 val = make_uint4(0, 0, 0, 0);
      if (ok) {
        u16 e0 = QKV[(u64)pixof(line, pb + 0) * 768 + choff + l];
        u16 e1 = QKV[(u64)pixof(line, pb + 1) * 768 + choff + l];
        u16 e2 = QKV[(u64)pixof(line, pb + 2) * 768 + choff + l];
        u16 e3 = QKV[(u64)pixof(line, pb + 3) * 768 + choff + l];
        u16 e4 = QKV[(u64)pixof(line, pb + 4) * 768 + choff + l];
        u16 e5 = QKV[(u64)pixof(line, pb + 5) * 768 + choff + l];
        u16 e6 = QKV[(u64)pixof(line, pb + 6) * 768 + choff + l];
        u16 e7 = QKV[(u64)pixof(line, pb + 7) * 768 + choff + l];
        val.x = (u32)e0 | ((u32)e1 << 16);
        val.y = (u32)e2 | ((u32)e3 << 16);
        val.z = (u32)e4 | ((u32)e5 << 16);
        val.w = (u32)e6 | ((u32)e7 << 16);
      }
      *(uint4*)(B + (((u32)(2 * pb)) ^ sw)) = val;
    }
  }
  __syncthreads();

  {
    u32 cA = (u32)hh * 16 + (u32)(l & 15);
    u32 rowb = cA * 256;
    u32 sw = (cA & 7) << 4;
    f32x4 m = {0.f, 0.f, 0.f, 0.f};
#pragma unroll
    for (int kc = 0; kc < 2; ++kc) {
      u32 pc = (u32)ph * 64 + (u32)kc * 32 + (u32)(l >> 4) * 8;
      u32 off = rowb + (((u32)(2 * pc)) ^ sw);
      bf16x8 ka = *(const bf16x8*)((const char*)BUF[0] + off);
      bf16x8 vb = *(const bf16x8*)((const char*)BUF[1] + off);
      m = __builtin_amdgcn_mfma_f32_16x16x32_bf16(ka, vb, m, 0, 0, 0);
    }
    *(f32x4*)&Mf[w][l & 15][(l >> 4) * 4] = m;
  }
  __syncthreads();

  if (tid < 256) {
    int ch = tid >> 6;
    int c2 = (tid >> 2) & 15;
    int c1g = (tid & 3) * 4;
    f32x4 a = *(const f32x4*)&Mf[ch][c2][c1g];
    f32x4 bb = *(const f32x4*)&Mf[ch + 4][c2][c1g];
    u16* dst = &Mt[ch][c2][c1g];
    dst[0] = f2bf(a[0] + bb[0]);
    dst[1] = f2bf(a[1] + bb[1]);
    dst[2] = f2bf(a[2] + bb[2]);
    dst[3] = f2bf(a[3] + bb[3]);
  }
  __syncthreads();

  union UB { uint4 u; bf16x8 v; } mb;
  mb.u = *(const uint4*)((const char*)Mt + (u32)hh * 1024 + (u32)(l & 15) * 64 +
                         (u32)(l >> 4) * 16);

  float wreg[9];
#pragma unroll
  for (int k = 0; k < 9; ++k) wreg[k] = lwS[k][l & 15];
  float lbias = lbS[l & 15];
  int nf = (t >> 2) & 3;
  int tp = (t & 112) | ((t & 3) << 2) | hh;
  u32 och = (u32)d * 64 + (u32)nf * 16 + (u32)(l & 15);
  u32 cc = (u32)hh * 16 + (u32)(l & 15);
  u32 ccb = cc * 256;
  u32 csw = (cc & 7) << 4;
  int g = l >> 4;

#pragma unroll
  for (int k = 0; k < 4; ++k) {
    int pt = ph * 4 + k;
    union UA { uint4 u; bf16x8 v; } qa;
    qa.u = qreg[k];
    f32x4 o = {0.f, 0.f, 0.f, 0.f};
    o = __builtin_amdgcn_mfma_f32_16x16x32_bf16(qa.v, mb.v, o, 0, 0, 0);

    int p0 = pt * 16 + g * 4;
    float tap[3][6];
    const u32 bufid[3] = {2u, 1u, 3u};
#pragma unroll
    for (int r = 0; r < 3; ++r) {
      const char* Bp = (const char*)BUF[bufid[r]] + ccb;
      union { uint2 u; u16 e[4]; } m4;
      m4.u = *(const uint2*)(Bp + (((u32)(2 * p0)) ^ csw));
      u32 alo = (p0 > 0) ? ((u32)(2 * (p0 - 1)) ^ csw) : csw;
      u32 ahi = (p0 < 124) ? ((u32)(2 * (p0 + 4)) ^ csw) : csw;
      u16 loe = *(const u16*)(Bp + alo);
      u16 hie = *(const u16*)(Bp + ahi);
      tap[r][0] = (p0 > 0) ? bf2f(loe) : 0.f;
      tap[r][1] = bf2f(m4.e[0]);
      tap[r][2] = bf2f(m4.e[1]);
      tap[r][3] = bf2f(m4.e[2]);
      tap[r][4] = bf2f(m4.e[3]);
      tap[r][5] = (p0 < 124) ? bf2f(hie) : 0.f;
    }
#pragma unroll
    for (int rr = 0; rr < 4; ++rr) {
      float acc = o[rr] + lbias;
#pragma unroll
      for (int r = 0; r < 3; ++r)
#pragma unroll
        for (int bb = 0; bb < 3; ++bb)
          acc += wreg[r * 3 + bb] * tap[r][rr + bb];
      int p = p0 + rr;
      int ho, wo;
      if (d == 2)      { ho = tp; wo = p; }
      else if (d == 0) { ho = p; wo = (tp - (p + 1)) & 127; }
      else if (d == 1) { ho = p; wo = (tp + (p + 1)) & 127; }
      else             { ho = p; wo = tp; }
      u32 opix = ((u32)(b * 128 + ho) << 7) + (u32)wo;
      Obuf[opix * 256 + och] = f2bf(acc);
    }
  }
}

// ---------------- launch ----------------
extern "C" void kernel_launch(void* const* d_in, const int* in_sizes, int n_in,
                              void* d_out, int out_size, void* d_ws, size_t ws_size,
                              hipStream_t stream) {
  (void)in_sizes; (void)n_in; (void)out_size; (void)ws_size;
  const float* x     = (const float*)d_in[0];
  const float* Wq    = (const float*)d_in[1];
  const float* bq    = (const float*)d_in[2];
  const float* Wkv   = (const float*)d_in[3];
  const float* bkv   = (const float*)d_in[4];
  const float* Wproj = (const float*)d_in[5];
  const float* bproj = (const float*)d_in[6];
  const float* lepe_w = (const float*)d_in[7];
  const float* lepe_b = (const float*)d_in[8];
  float* out = (float*)d_out;

  char* ws = (char*)d_ws;
  u16* Xbf   = (u16*)(ws + 0);           //  65536x256 bf16 = 32 MB
  u16* QKV   = (u16*)(ws + 33554432);    //  65536x768 bf16 = 96 MB
  u16* Obuf  = (u16*)(ws + 134217728);   //  65536x256 bf16 = 32 MB
  u16* W1t   = (u16*)(ws + 167772160);   //  768x256 bf16
  u16* Wpt   = (u16*)(ws + 168165376);   //  256x256 bf16
  float* b1  = (float*)(ws + 168296448); //  768 f32

  k_convert_x<<<2048, 256, 0, stream>>>((const float4*)x, (uint2*)Xbf, 16777216 / 4);
  k_prep_w<<<1024, 256, 0, stream>>>(Wq, bq, Wkv, bkv, Wproj, W1t, b1, Wpt);
  k_gemm<<<512 * 6, 256, 0, stream>>>(Xbf, W1t, b1, QKV, 768, 1);
  k_attn<<<2048, 512, 0, stream>>>(QKV, lepe_w, lepe_b, Obuf);
  k_gemm<<<512 * 2, 256, 0, stream>>>(Obuf, Wpt, bproj, out, 256, 0);
}

// Round 6
// 141.865 us; speedup vs baseline: 2.3523x; 1.0742x over previous
//
#include <hip/hip_runtime.h>

typedef unsigned short u16;
typedef unsigned int u32;
typedef unsigned long long u64;
typedef __bf16 bf16x8 __attribute__((ext_vector_type(8)));
typedef float f32x4 __attribute__((ext_vector_type(4)));

__device__ __forceinline__ u16 f2bf(float f) {
  u32 u = __float_as_uint(f);
  return (u16)((u + 0x7fffu + ((u >> 16) & 1u)) >> 16);  // RNE
}
__device__ __forceinline__ float bf2f(u16 h) {
  return __uint_as_float(((u32)h) << 16);
}

// async global->LDS, 16B per lane; LDS dest = wave-uniform base + lane*16,
// global src is PER-LANE (verified in k_gemm R5 + guide m173)
__device__ __forceinline__ void glds16(const void* g, void* s) {
  __builtin_amdgcn_global_load_lds(
      (__attribute__((address_space(1))) void*)(u64)g,
      (__attribute__((address_space(3))) void*)(u32)(u64)s, 16, 0, 0);
}

// ---------------- x: fp32 -> bf16 ----------------
__global__ __launch_bounds__(256) void k_convert_x(const float4* __restrict__ x4,
                                                   uint2* __restrict__ o4, int n4) {
  int i = blockIdx.x * 256 + threadIdx.x;
  int stride = gridDim.x * 256;
  for (; i < n4; i += stride) {
    float4 v = x4[i];
    uint2 o;
    o.x = (u32)f2bf(v.x) | ((u32)f2bf(v.y) << 16);
    o.y = (u32)f2bf(v.z) | ((u32)f2bf(v.w) << 16);
    o4[i] = o;
  }
}

// ---------------- weight prep ----------------
__global__ __launch_bounds__(256) void k_prep_w(
    const float* __restrict__ Wq, const float* __restrict__ bq,
    const float* __restrict__ Wkv, const float* __restrict__ bkv,
    const float* __restrict__ Wproj,
    u16* __restrict__ W1t, float* __restrict__ b1, u16* __restrict__ Wpt) {
  int n = blockIdx.x, k = threadIdx.x;
  if (n < 768) {
    float v = (n < 256) ? Wq[k * 256 + n] * 0.125f : Wkv[k * 512 + (n - 256)];
    W1t[n * 256 + k] = f2bf(v);
    if (k == 0) b1[n] = (n < 256) ? bq[n] * 0.125f : bkv[n - 256];
  } else {
    int nn = n - 768;
    Wpt[nn * 256 + k] = f2bf(Wproj[k * 256 + nn]);
  }
}

// ---------------- GEMM (R5 VERIFIED version, unchanged) ----------------
__global__ __launch_bounds__(256) void k_gemm(const u16* __restrict__ A,
                                              const u16* __restrict__ Bt,
                                              const float* __restrict__ bias,
                                              void* __restrict__ Cout,
                                              int N, int out_bf16) {
  __shared__ u16 As[128 * 32];
  __shared__ u16 Bs[128 * 32];
  int nt = N >> 7;
  int nwg = gridDim.x;
  int bid = blockIdx.x;
  int swz = (bid & 7) * (nwg >> 3) + (bid >> 3);
  int mt = swz / nt;
  int ntile = swz - mt * nt;
  int tid = threadIdx.x;
  int lane = tid & 63, wid = tid >> 6;
  int wm = wid >> 1, wn = wid & 1;
  size_t mbase = (size_t)mt << 7;
  int nbase = ntile << 7;
  int lrow = tid >> 2;
  int lch = (tid & 3) << 3;

  const u16* ag = A + (mbase + (size_t)lrow) * 256 + lch;
  const u16* bg = Bt + ((size_t)(nbase + lrow)) * 256 + lch;
  u32 wbase = ((u32)wid) << 9;

  f32x4 acc[4][4] = {};

  for (int kb = 0; kb < 8; ++kb) {
    __syncthreads();
    glds16(ag + kb * 32, As + wbase);
    glds16(ag + 64 * 256 + kb * 32, As + 2048 + wbase);
    glds16(bg + kb * 32, Bs + wbase);
    glds16(bg + 64 * 256 + kb * 32, Bs + 2048 + wbase);
    __syncthreads();
    int r = lane & 15, kq = (lane >> 4) << 3;
    bf16x8 af[4], bfv[4];
#pragma unroll
    for (int m = 0; m < 4; ++m)
      af[m] = *(const bf16x8*)(As + (wm * 64 + m * 16 + r) * 32 + kq);
#pragma unroll
    for (int n = 0; n < 4; ++n)
      bfv[n] = *(const bf16x8*)(Bs + (wn * 64 + n * 16 + r) * 32 + kq);
#pragma unroll
    for (int m = 0; m < 4; ++m)
#pragma unroll
      for (int n = 0; n < 4; ++n)
        acc[m][n] = __builtin_amdgcn_mfma_f32_16x16x32_bf16(af[m], bfv[n], acc[m][n], 0, 0, 0);
  }

  int cg4 = (lane >> 4) << 2;
  int cl = lane & 15;
#pragma unroll
  for (int m = 0; m < 4; ++m)
#pragma unroll
    for (int n = 0; n < 4; ++n) {
      size_t row0 = mbase + wm * 64 + m * 16 + cg4;
      int col = nbase + wn * 64 + n * 16 + cl;
      float bv = bias[col];
#pragma unroll
      for (int rr = 0; rr < 4; ++rr) {
        float v = acc[m][n][rr] + bv;
        if (out_bf16) ((u16*)Cout)[(row0 + rr) * (size_t)N + col] = f2bf(v);
        else ((float*)Cout)[(row0 + rr) * (size_t)N + col] = v;
      }
    }
}

// ---------------- attention + LePE ----------------
// Same structure/math as R5 (verified), but staging via global_load_lds into
// ROW-MAJOR linear LDS [p][64ch] (one 128B line per position). Phase-1 frags
// and conv taps assemble from column-slices (scalar ds_reads); identical
// element values to R5's column-major reads. Write-back permutation verified.
__global__ __launch_bounds__(512) void k_attn(const u16* __restrict__ QKV,
                                              const float* __restrict__ lepe_w,
                                              const float* __restrict__ lepe_b,
                                              u16* __restrict__ Obuf) {
  __shared__ u16 BUF[4][128 * 64];   // 0:K 1:Vo 2:Vm 3:Vp, row-major [p][c]
  __shared__ float Mf[8][16][16];    // per-wave partial M (f32)
  __shared__ u16 Mt[4][16][32];      // M^T bf16, K-padded to 32
  __shared__ float lwS[9][16];
  __shared__ float lbS[16];

  int bid = blockIdx.x;
  int t = bid & 127, b = (bid >> 7) & 3, d = bid >> 9;
  int tid = threadIdx.x;
  int w = tid >> 6, l = tid & 63;
  int hh = w & 3, ph = w >> 2;

  ((u32*)Mt)[tid] = 0;
  ((u32*)Mt)[tid + 512] = 0;
  if (tid < 144) lwS[tid >> 4][tid & 15] = lepe_w[(tid & 15) * 9 + (tid >> 4)];
  if (tid < 16) lbS[tid] = lepe_b[tid];

  auto pixof = [&](int line, int p) -> u32 {
    int h, ww;
    if (d == 2)      { h = line; ww = p; }
    else if (d == 0) { h = p; ww = (line - (p + 1)) & 127; }
    else if (d == 1) { h = p; ww = (line + (p + 1)) & 127; }
    else             { h = p; ww = line; }
    return ((u32)(b * 128 + h) << 7) + (u32)ww;
  };

  // ---- Q prefetch into regs (unchanged from R5) ----
  uint4 qreg[4];
  u32 qch = (u32)d * 64 + (u32)hh * 16 + (u32)((l >> 4) & 1) * 8;
#pragma unroll
  for (int k = 0; k < 4; ++k) {
    int p = (ph * 4 + k) * 16 + (l & 15);
    qreg[k] = *(const uint4*)(QKV + (u64)pixof(t, p) * 768 + qch);
  }

  // ---- stage via global_load_lds: wave w -> buffer w&3, p-half w>>2 ----
  {
    int bf = w & 3;
    int line = t;
    u32 choff = (bf == 0) ? (256u + d * 64) : (512u + d * 64);
    bool ok = true;
    if (bf == 2) { line = t - 16; ok = (t >> 4) > 0; }
    if (bf == 3) { line = t + 16; ok = (t >> 4) < 7; }
    u16* Bb = &BUF[bf][0];
    int phh = (w >> 2) * 64;
#pragma unroll
    for (int it = 0; it < 8; ++it) {
      int p0 = phh + it * 8;   // wave-uniform
      if (ok) {
        const u16* g = QKV + (u64)pixof(line, p0 + (l >> 3)) * 768 + choff + (l & 7) * 8;
        glds16(g, Bb + p0 * 64);   // lane lands at (p0 + l>>3)*128B + (l&7)*16B
      } else {
        *(uint4*)(Bb + p0 * 64 + l * 8) = make_uint4(0, 0, 0, 0);
      }
    }
  }
  __syncthreads();

  // ---- phase 1: wave w = (head hh, p-half ph): partial M = K^T V ----
  {
    u32 cA = (u32)hh * 16 + (u32)(l & 15);
    f32x4 m = {0.f, 0.f, 0.f, 0.f};
#pragma unroll
    for (int kc = 0; kc < 2; ++kc) {
      u32 pc = (u32)ph * 64 + (u32)kc * 32 + (u32)(l >> 4) * 8;
      union { u16 e[8]; bf16x8 v; } ka, vb;
#pragma unroll
      for (int e = 0; e < 8; ++e) {
        ka.e[e] = BUF[0][(pc + e) * 64 + cA];
        vb.e[e] = BUF[1][(pc + e) * 64 + cA];
      }
      m = __builtin_amdgcn_mfma_f32_16x16x32_bf16(ka.v, vb.v, m, 0, 0, 0);
    }
    *(f32x4*)&Mf[w][l & 15][(l >> 4) * 4] = m;
  }
  __syncthreads();

  // ---- combine halves -> Mt bf16 (unchanged) ----
  if (tid < 256) {
    int ch = tid >> 6;
    int c2 = (tid >> 2) & 15;
    int c1g = (tid & 3) * 4;
    f32x4 a = *(const f32x4*)&Mf[ch][c2][c1g];
    f32x4 bb = *(const f32x4*)&Mf[ch + 4][c2][c1g];
    u16* dst = &Mt[ch][c2][c1g];
    dst[0] = f2bf(a[0] + bb[0]);
    dst[1] = f2bf(a[1] + bb[1]);
    dst[2] = f2bf(a[2] + bb[2]);
    dst[3] = f2bf(a[3] + bb[3]);
  }
  __syncthreads();

  // ---- phase 2: O = Q*M + LePE conv + permuted store (math unchanged) ----
  union UB { uint4 u; bf16x8 v; } mb;
  mb.u = *(const uint4*)((const char*)Mt + (u32)hh * 1024 + (u32)(l & 15) * 64 +
                         (u32)(l >> 4) * 16);

  float wreg[9];
#pragma unroll
  for (int k = 0; k < 9; ++k) wreg[k] = lwS[k][l & 15];
  float lbias = lbS[l & 15];
  int nf = (t >> 2) & 3;
  int tp = (t & 112) | ((t & 3) << 2) | hh;
  u32 och = (u32)d * 64 + (u32)nf * 16 + (u32)(l & 15);
  u32 cc = (u32)hh * 16 + (u32)(l & 15);
  int g = l >> 4;

#pragma unroll
  for (int k = 0; k < 4; ++k) {
    int pt = ph * 4 + k;
    union UA { uint4 u; bf16x8 v; } qa;
    qa.u = qreg[k];
    f32x4 o = {0.f, 0.f, 0.f, 0.f};
    o = __builtin_amdgcn_mfma_f32_16x16x32_bf16(qa.v, mb.v, o, 0, 0, 0);

    int p0 = pt * 16 + g * 4;
    // conv taps from row-major buffers: rows {Vm(2), Vo(1), Vp(3)}, p0-1..p0+4
    float tap[3][6];
    const u32 bufid[3] = {2u, 1u, 3u};
#pragma unroll
    for (int r = 0; r < 3; ++r) {
      const u16* Bp = &BUF[bufid[r]][0];
#pragma unroll
      for (int j = 0; j < 6; ++j) {
        int pr = p0 - 1 + j;
        bool okr = (pr >= 0) && (pr < 128);
        tap[r][j] = okr ? bf2f(Bp[(u32)pr * 64 + cc]) : 0.f;
      }
    }
#pragma unroll
    for (int rr = 0; rr < 4; ++rr) {
      float acc = o[rr] + lbias;
#pragma unroll
      for (int r = 0; r < 3; ++r)
#pragma unroll
        for (int bb = 0; bb < 3; ++bb)
          acc += wreg[r * 3 + bb] * tap[r][rr + bb];
      int p = p0 + rr;
      int ho, wo;
      if (d == 2)      { ho = tp; wo = p; }
      else if (d == 0) { ho = p; wo = (tp - (p + 1)) & 127; }
      else if (d == 1) { ho = p; wo = (tp + (p + 1)) & 127; }
      else             { ho = p; wo = tp; }
      u32 opix = ((u32)(b * 128 + ho) << 7) + (u32)wo;
      Obuf[opix * 256 + och] = f2bf(acc);
    }
  }
}

// ---------------- launch ----------------
extern "C" void kernel_launch(void* const* d_in, const int* in_sizes, int n_in,
                              void* d_out, int out_size, void* d_ws, size_t ws_size,
                              hipStream_t stream) {
  (void)in_sizes; (void)n_in; (void)out_size; (void)ws_size;
  const float* x     = (const float*)d_in[0];
  const float* Wq    = (const float*)d_in[1];
  const float* bq    = (const float*)d_in[2];
  const float* Wkv   = (const float*)d_in[3];
  const float* bkv   = (const float*)d_in[4];
  const float* Wproj = (const float*)d_in[5];
  const float* bproj = (const float*)d_in[6];
  const float* lepe_w = (const float*)d_in[7];
  const float* lepe_b = (const float*)d_in[8];
  float* out = (float*)d_out;

  char* ws = (char*)d_ws;
  u16* Xbf   = (u16*)(ws + 0);           //  65536x256 bf16 = 32 MB
  u16* QKV   = (u16*)(ws + 33554432);    //  65536x768 bf16 = 96 MB
  u16* Obuf  = (u16*)(ws + 134217728);   //  65536x256 bf16 = 32 MB
  u16* W1t   = (u16*)(ws + 167772160);   //  768x256 bf16
  u16* Wpt   = (u16*)(ws + 168165376);   //  256x256 bf16
  float* b1  = (float*)(ws + 168296448); //  768 f32

  k_convert_x<<<2048, 256, 0, stream>>>((const float4*)x, (uint2*)Xbf, 16777216 / 4);
  k_prep_w<<<1024, 256, 0, stream>>>(Wq, bq, Wkv, bkv, Wproj, W1t, b1, Wpt);
  k_gemm<<<512 * 6, 256, 0, stream>>>(Xbf, W1t, b1, QKV, 768, 1);
  k_attn<<<2048, 512, 0, stream>>>(QKV, lepe_w, lepe_b, Obuf);
  k_gemm<<<512 * 2, 256, 0, stream>>>(Obuf, Wpt, bproj, out, 256, 0);
}